// Round 14
// baseline (74.903 us; speedup 1.0000x reference)
//
#include <hip/hip_runtime.h>
#include <hip/hip_bf16.h>

// CharLSTM: B=128, TW=256, TC=25, V=128, D=32, H=64 (4H=256), N=32768 seqs.
//
// R14 = R13 math in a BARRIER-FREE 1-wave-block structure:
//  R13 diagnosis: 24% issue-idle from barrier-lockstep phase alignment
//  (co-resident blocks' waves all do trans together, then all MFMA).
//  Fix: block = 1 wave = 16 sequences. The wave computes all 16 tiles
//  itself (4 unit-groups x 4 gates), so h never crosses waves ->
//  NO __syncthreads anywhere. Same-wave LDS RAW ordered by lgkmcnt.
//  Single 2KB h buffer (A-frags read to regs before any h_t write).
//  Per-group interleave MFMA(ug) / ACT(ug-1) mixes matrix + trans pipes
//  inside one wave; 2 independent waves/SIMD self-stagger the rest.
//  Register risk: bh = 128 VGPR, total ~240/256 (2 waves/SIMD tier).
//  Tripwire: WRITE_SIZE >> 8.4 MB => spills => revert to R13 (72.3 us).

#define TC_LEN 25
#define H_N 64
#define D_N 32
#define G4_N 256
#define V_N 128

typedef __attribute__((ext_vector_type(8))) short bf16x8;
typedef __attribute__((ext_vector_type(4))) float f32x4;
typedef __attribute__((ext_vector_type(2))) float f32x2;
typedef __attribute__((ext_vector_type(4))) int i32x4;

#define SCALE_SIG (-1.4426950408889634f)   /* -log2(e)  */
#define SCALE_G   ( 2.8853900817779268f)   /* 2*log2(e) */

__device__ __forceinline__ ushort bf16_rne(float x) {
    const uint u = __float_as_uint(x);
    return (ushort)((u + 0x7fffu + ((u >> 16) & 1u)) >> 16);
}
__device__ __forceinline__ float bf16_tof(ushort h) {
    return __uint_as_float(((uint)h) << 16);
}
// swizzled byte offset into a [16][64] bf16 (2 KB) tile
__device__ __forceinline__ int hswz(int row, int kbyte) {
    const int b = row * 128 + kbyte;
    return b ^ ((row & 7) << 4);
}

// ---- prologue 1: EWr[v][c16][tile] = ((E.W)[v][tile*64+c16]+b)*gate_scale ----
__global__ void ew_precompute(const float* __restrict__ E,
                              const float* __restrict__ W,
                              const float* __restrict__ b,
                              float* __restrict__ EWr) {
    const int v = blockIdx.x;
    const int j = threadIdx.x;           // output col = (j>>6)*64 + (j&63)
    float acc = b[j];
#pragma unroll
    for (int d = 0; d < D_N; ++d)
        acc = fmaf(E[v * D_N + d], W[d * G4_N + j], acc);
    const int tile = j >> 6, c16 = j & 63;
    const float scale = (tile == 2) ? SCALE_G : SCALE_SIG;
    EWr[v * G4_N + c16 * 4 + tile] = acc * scale;
}

// ---- prologue 2: Upk[col][k] bf16-hi, pre-scaled ----
__global__ void u_pack(const float* __restrict__ U, ushort* __restrict__ Upk) {
    const int k   = blockIdx.x;          // 0..63
    const int col = threadIdx.x;         // 0..255
    const float scale = ((col >> 6) == 2) ? SCALE_G : SCALE_SIG;
    const float uv = U[k * G4_N + col] * scale;
    Upk[col * 64 + k] = bf16_rne(uv);
}

__global__ __launch_bounds__(64, 2) void char_lstm_wave(
    const int* __restrict__ chars,    // [N][25]
    const ushort* __restrict__ Upk,   // [256][64] bf16-hi frag table
    const float* __restrict__ EWr,    // [128][64][4] permuted+scaled
    float* __restrict__ out)          // [N][64]
{
    const int l = threadIdx.x;       // lane
    const int q = l >> 4;            // lane group 0..3
    const int n16 = l & 15;          // 0..15
    const int seq0 = blockIdx.x * 16;

    __shared__ int ibuf[TC_LEN][16];         // byte offsets, 1.6 KB
    __shared__ ushort hbuf[16 * H_N];        // bf16 h, SINGLE buffer, 2 KB

    // stage chars transposed as EWr BYTE offsets (row stride 1024)
    for (int idx = l; idx < TC_LEN * 16; idx += 64) {
        const int s = idx & 15, tt = idx >> 4;
        ibuf[tt][s] = chars[(seq0 + s) * TC_LEN + tt] << 10;
    }

    // ---- ALL 16 tiles of U-hi fragments: bh[ug][gate][ks], 128 VGPR ----
    bf16x8 bh[4][4][2];
#pragma unroll
    for (int ug = 0; ug < 4; ++ug)
#pragma unroll
        for (int g = 0; g < 4; ++g) {
            const ushort* ub = Upk + (g * 64 + ug * 16 + n16) * 64 + 8 * q;
            bh[ug][g][0] = *(const bf16x8*)(ub);
            bh[ug][g][1] = *(const bf16x8*)(ub + 32);
        }

    // hoisted offsets
    const int offA0 = hswz(n16, 16 * q);
    const int offA1 = hswz(n16, 64 + 16 * q);
    int rowb[4], rswz[4];
#pragma unroll
    for (int r = 0; r < 4; ++r) {
        rowb[r] = (4 * q + r) * 128;
        rswz[r] = ((4 * q + r) & 7) << 4;
    }
    const int  colw   = n16 * 2;
    const uint colb0  = (uint)(n16 * 16);
    const char* ewbase = (const char*)EWr;   // uniform -> SGPR pair
    char* hb = (char*)hbuf;
    float* outb = out + (seq0 + 4 * q) * H_N + n16;

    f32x2 cP[4][2];
#pragma unroll
    for (int ug = 0; ug < 4; ++ug) {
        cP[ug][0] = (f32x2){0.0f, 0.0f};
        cP[ug][1] = (f32x2){0.0f, 0.0f};
    }
    f32x4 acc[4];
    f32x4 ewv[2][4];
    const f32x4 zero4 = {0.0f, 0.0f, 0.0f, 0.0f};

#define EW_LOAD(PP, UG)                                                       \
    {                                                                         \
        _Pragma("unroll")                                                     \
        for (int r = 0; r < 4; ++r)                                           \
            ewv[PP][r] = *(const f32x4*)(ewbase + (uint)cv[r] + colb0 +       \
                                         (UG) * 256u);                        \
    }

#define MFMA_G(UG)                                                            \
    {                                                                         \
        __builtin_amdgcn_s_setprio(1);                                        \
        _Pragma("unroll")                                                     \
        for (int g = 0; g < 4; ++g)                                           \
            acc[g] = __builtin_amdgcn_mfma_f32_16x16x32_bf16(                 \
                ah0, bh[UG][g][0], zero4, 0, 0, 0);                           \
        _Pragma("unroll")                                                     \
        for (int g = 0; g < 4; ++g)                                           \
            acc[g] = __builtin_amdgcn_mfma_f32_16x16x32_bf16(                 \
                ah1, bh[UG][g][1], acc[g], 0, 0, 0);                          \
        __builtin_amdgcn_s_setprio(0);                                        \
    }

    // activation for one unit-group: 4 cells (rows 4q..4q+3, unit UG*16+n16)
#define ACT_G(UG, PP, ADD_EW, WRITE_OUT)                                      \
    {                                                                         \
        _Pragma("unroll")                                                     \
        for (int p = 0; p < 2; ++p) {                                         \
            const int r0 = 2 * p, r1 = 2 * p + 1;                             \
            f32x2 z0, z1, z2, z3;                                             \
            if (ADD_EW) {                                                     \
                z0[0] = acc[0][r0] + ewv[PP][r0][0]; z0[1] = acc[0][r1] + ewv[PP][r1][0]; \
                z1[0] = acc[1][r0] + ewv[PP][r0][1]; z1[1] = acc[1][r1] + ewv[PP][r1][1]; \
                z2[0] = acc[2][r0] + ewv[PP][r0][2]; z2[1] = acc[2][r1] + ewv[PP][r1][2]; \
                z3[0] = acc[3][r0] + ewv[PP][r0][3]; z3[1] = acc[3][r1] + ewv[PP][r1][3]; \
            } else {                                                          \
                z0[0] = ewv[PP][r0][0]; z0[1] = ewv[PP][r1][0];               \
                z1[0] = ewv[PP][r0][1]; z1[1] = ewv[PP][r1][1];               \
                z2[0] = ewv[PP][r0][2]; z2[1] = ewv[PP][r1][2];               \
                z3[0] = ewv[PP][r0][3]; z3[1] = ewv[PP][r1][3];               \
            }                                                                 \
            f32x2 A, B, C, D;                                                 \
            A[0] = __builtin_amdgcn_exp2f(z0[0]); A[1] = __builtin_amdgcn_exp2f(z0[1]); \
            B[0] = __builtin_amdgcn_exp2f(z1[0]); B[1] = __builtin_amdgcn_exp2f(z1[1]); \
            C[0] = __builtin_amdgcn_exp2f(z2[0]); C[1] = __builtin_amdgcn_exp2f(z2[1]); \
            D[0] = __builtin_amdgcn_exp2f(z3[0]); D[1] = __builtin_amdgcn_exp2f(z3[1]); \
            const f32x2 di = A + 1.0f, df = B + 1.0f, dg = C + 1.0f;          \
            const f32x2 m1 = di * dg;                                         \
            const f32x2 num = cP[UG][p] * m1 + (C - 1.0f) * df;               \
            const f32x2 qa = m1 * df;                                         \
            f32x2 Q;                                                          \
            Q[0] = __builtin_amdgcn_rcpf(qa[0]);                              \
            Q[1] = __builtin_amdgcn_rcpf(qa[1]);                              \
            cP[UG][p] = num * Q;                                              \
            const f32x2 cs = cP[UG][p] * SCALE_G;                             \
            f32x2 E2;                                                         \
            E2[0] = __builtin_amdgcn_exp2f(cs[0]);                            \
            E2[1] = __builtin_amdgcn_exp2f(cs[1]);                            \
            const f32x2 nh = E2 - 1.0f;                                       \
            const f32x2 Ph = (D + 1.0f) * (E2 + 1.0f);                        \
            f32x2 R;                                                          \
            R[0] = __builtin_amdgcn_rcpf(Ph[0]);                              \
            R[1] = __builtin_amdgcn_rcpf(Ph[1]);                              \
            const f32x2 h = nh * R;                                           \
            _Pragma("unroll")                                                 \
            for (int e = 0; e < 2; ++e) {                                     \
                const int r = 2 * p + e;                                      \
                if (WRITE_OUT) {                                              \
                    outb[r * H_N + (UG) * 16] = h[e];                         \
                } else {                                                      \
                    *(ushort*)(hb + rowb[r] +                                 \
                               (((UG) * 32 + colw) ^ rswz[r])) =              \
                        bf16_rne(h[e]);                                       \
                }                                                             \
            }                                                                 \
        }                                                                     \
    }

    // per-timestep body (t>=1): A-frags to regs FIRST (then h writes safe),
    // EW loads one group ahead (ping/pong), MFMA(ug) interleaved ACT(ug-1)
#define TS_BODY(T, WO)                                                        \
    {                                                                         \
        const i32x4 cv = *(const i32x4*)&ibuf[(T)][4 * q];                    \
        const bf16x8 ah0 = *(const bf16x8*)(hb + offA0);                      \
        const bf16x8 ah1 = *(const bf16x8*)(hb + offA1);                      \
        EW_LOAD(0, 0);                                                        \
        MFMA_G(0);                                                            \
        EW_LOAD(1, 1);                                                        \
        ACT_G(0, 0, 1, WO);                                                   \
        MFMA_G(1);                                                            \
        EW_LOAD(0, 2);                                                        \
        ACT_G(1, 1, 1, WO);                                                   \
        MFMA_G(2);                                                            \
        EW_LOAD(1, 3);                                                        \
        ACT_G(2, 0, 1, WO);                                                   \
        MFMA_G(3);                                                            \
        ACT_G(3, 1, 1, WO);                                                   \
    }

    // ---- t = 0 (peeled): z = x-proj only, h0 -> hbuf ----
    {
        const i32x4 cv = *(const i32x4*)&ibuf[0][4 * q];
        EW_LOAD(0, 0);
        EW_LOAD(1, 1);
        ACT_G(0, 0, 0, 0);
        EW_LOAD(0, 2);
        ACT_G(1, 1, 0, 0);
        EW_LOAD(1, 3);
        ACT_G(2, 0, 0, 0);
        ACT_G(3, 1, 0, 0);
    }

    // ---- t = 1..23 ----
    for (int t = 1; t < 24; ++t) {
        TS_BODY(t, 0);
    }

    // ---- t = 24: h_last straight to global ----
    TS_BODY(24, 1);

#undef EW_LOAD
#undef MFMA_G
#undef ACT_G
#undef TS_BODY
}

extern "C" void kernel_launch(void* const* d_in, const int* in_sizes, int n_in,
                              void* d_out, int out_size, void* d_ws, size_t ws_size,
                              hipStream_t stream) {
    const int*   chars = (const int*)d_in[0];
    const float* E     = (const float*)d_in[1];
    const float* W     = (const float*)d_in[2];
    const float* U     = (const float*)d_in[3];
    const float* b     = (const float*)d_in[4];
    float* out = (float*)d_out;
    float*  EWr = (float*)d_ws;                         // 131072 B
    ushort* Upk = (ushort*)((char*)d_ws + 131072);      // 32768 B

    const int N = in_sizes[0] / TC_LEN;             // 32768
    const int blocks = N / 16;                      // 2048 one-wave blocks

    ew_precompute<<<V_N, G4_N, 0, stream>>>(E, W, b, EWr);
    u_pack<<<H_N, G4_N, 0, stream>>>(U, Upk);
    char_lstm_wave<<<blocks, 64, 0, stream>>>(chars, Upk, EWr, out);
}

// Round 15
// 71.148 us; speedup vs baseline: 1.0528x; 1.0528x over previous
//
#include <hip/hip_runtime.h>
#include <hip/hip_bf16.h>

// CharLSTM: B=128, TW=256, TC=25, V=128, D=32, H=64 (4H=256), N=32768 seqs.
//
// R15 = R13 (best: 72.3 us) + barrier-drain fix:
//  R14's null result (barriers removed entirely -> fill did NOT improve)
//  refuted the lockstep theory; the real stall is __syncthreads' implicit
//  s_waitcnt vmcnt(0): EW prefetch loads issued just before the barrier
//  must return from L2 (~200 cyc) while ALL waves wait. Fix:
//  - raw `s_waitcnt lgkmcnt(0); s_barrier` (LDS drained for cross-wave
//    h correctness; global EW loads stay in flight across the barrier -
//    they're read-only data, no cross-wave hazard; compiler inserts
//    vmcnt(N) before ewv's use next timestep, ~500 cyc of slack).
//  - ewv ping-pong (ewvA/ewvB): prefetch issues right after the MFMA
//    cluster, before ACT, without clobbering the live copy. +16 VGPR,
//    combined ~116 regs still in the <=128 4-waves/SIMD tier.

#define SEQ_M 16
#define TC_LEN 25
#define H_N 64
#define D_N 32
#define G4_N 256
#define V_N 128

typedef __attribute__((ext_vector_type(8))) short bf16x8;
typedef __attribute__((ext_vector_type(4))) float f32x4;
typedef __attribute__((ext_vector_type(2))) float f32x2;
typedef __attribute__((ext_vector_type(4))) int i32x4;

#define SCALE_SIG (-1.4426950408889634f)   /* -log2(e)  */
#define SCALE_G   ( 2.8853900817779268f)   /* 2*log2(e) */

// LDS-only barrier: drain LDS ops (cross-wave h exchange) but let
// global (EW) loads stay outstanding across the barrier.
#define LBAR() asm volatile("s_waitcnt lgkmcnt(0)\n\ts_barrier" ::: "memory")

__device__ __forceinline__ ushort bf16_rne(float x) {
    const uint u = __float_as_uint(x);
    return (ushort)((u + 0x7fffu + ((u >> 16) & 1u)) >> 16);
}
__device__ __forceinline__ float bf16_tof(ushort h) {
    return __uint_as_float(((uint)h) << 16);
}
// swizzled byte offset into a [16][64] bf16 (2 KB) tile
__device__ __forceinline__ int hswz(int row, int kbyte) {
    const int b = row * 128 + kbyte;
    return b ^ ((row & 7) << 4);
}

// ---- prologue 1: EWr[v][c16][tile] = ((E.W)[v][tile*64+c16]+b)*gate_scale ----
__global__ void ew_precompute(const float* __restrict__ E,
                              const float* __restrict__ W,
                              const float* __restrict__ b,
                              float* __restrict__ EWr) {
    const int v = blockIdx.x;
    const int j = threadIdx.x;           // output col = (j>>6)*64 + (j&63)
    float acc = b[j];
#pragma unroll
    for (int d = 0; d < D_N; ++d)
        acc = fmaf(E[v * D_N + d], W[d * G4_N + j], acc);
    const int tile = j >> 6, c16 = j & 63;
    const float scale = (tile == 2) ? SCALE_G : SCALE_SIG;
    EWr[v * G4_N + c16 * 4 + tile] = acc * scale;
}

// ---- prologue 2: Upk[col][k] bf16-hi, pre-scaled ----
__global__ void u_pack(const float* __restrict__ U, ushort* __restrict__ Upk) {
    const int k   = blockIdx.x;          // 0..63
    const int col = threadIdx.x;         // 0..255
    const float scale = ((col >> 6) == 2) ? SCALE_G : SCALE_SIG;
    const float uv = U[k * G4_N + col] * scale;
    Upk[col * 64 + k] = bf16_rne(uv);
}

__global__ __launch_bounds__(256, 4) void char_lstm_mfma(
    const int* __restrict__ chars,    // [N][25]
    const ushort* __restrict__ Upk,   // [256][64] bf16-hi frag table
    const float* __restrict__ EWr,    // [128][64][4] permuted+scaled
    float* __restrict__ out)          // [N][64]
{
    const int j = threadIdx.x;
    const int w = j >> 6;            // wave 0..3
    const int l = j & 63;            // lane
    const int q = l >> 4;            // lane group 0..3
    const int n16 = l & 15;          // 0..15
    const int c16 = w * 16 + n16;    // this thread's unit/col-in-gate
    const int seq0 = blockIdx.x * SEQ_M;

    __shared__ int ibuf[TC_LEN][SEQ_M];              // byte offsets
    __shared__ ushort hbuf[2][SEQ_M * H_N];          // [buf], bf16-RNE h, 4 KB

    // stage chars transposed as EWr BYTE offsets (row stride 256*4 = 1024)
    for (int idx = j; idx < TC_LEN * SEQ_M; idx += 256) {
        const int s = idx & 15, tt = idx >> 4;
        ibuf[tt][s] = chars[(seq0 + s) * TC_LEN + tt] << 10;
    }

    // ---- load pre-packed U-hi fragments: 8x dwordx4, L2-hot ----
    bf16x8 bh[4][2];
#pragma unroll
    for (int tile = 0; tile < 4; ++tile) {
        const ushort* ub = Upk + (tile * 64 + c16) * 64 + 8 * q;
#pragma unroll
        for (int ks = 0; ks < 2; ++ks)
            bh[tile][ks] = *(const bf16x8*)(ub + ks * 32);
    }

    __syncthreads();   // ibuf visible (full barrier once, prologue only)

    // hoisted LDS offsets + uniform EW base with 32-bit per-lane offsets
    const int offA0 = hswz(n16, 16 * q);
    const int offA1 = hswz(n16, 64 + 16 * q);
    int offW[4];
#pragma unroll
    for (int r = 0; r < 4; ++r) offW[r] = hswz(4 * q + r, c16 * 2);
    const char* ewbase = (const char*)EWr;     // uniform -> SGPR pair
    const uint  c16b   = (uint)(c16 * 16);     // per-lane 32-bit bias

    f32x2 cP[2] = {{0.0f, 0.0f}, {0.0f, 0.0f}};
    f32x4 ewvA[4], ewvB[4];
    f32x4 acc[4];
    const f32x4 zero4 = {0.0f, 0.0f, 0.0f, 0.0f};

    // activation: z = (ADD_EW ? acc+ew : ew), packed f32x2 over r-pairs
#define ACT_BODY(HN, EWV, ADD_EW, WRITE_OUT)                                  \
    {                                                                         \
        _Pragma("unroll")                                                     \
        for (int p = 0; p < 2; ++p) {                                         \
            const int r0 = 2 * p, r1 = 2 * p + 1;                             \
            f32x2 z0, z1, z2, z3;                                             \
            if (ADD_EW) {                                                     \
                z0[0] = acc[0][r0] + EWV[r0][0]; z0[1] = acc[0][r1] + EWV[r1][0]; \
                z1[0] = acc[1][r0] + EWV[r0][1]; z1[1] = acc[1][r1] + EWV[r1][1]; \
                z2[0] = acc[2][r0] + EWV[r0][2]; z2[1] = acc[2][r1] + EWV[r1][2]; \
                z3[0] = acc[3][r0] + EWV[r0][3]; z3[1] = acc[3][r1] + EWV[r1][3]; \
            } else {                                                          \
                z0[0] = EWV[r0][0]; z0[1] = EWV[r1][0];                       \
                z1[0] = EWV[r0][1]; z1[1] = EWV[r1][1];                       \
                z2[0] = EWV[r0][2]; z2[1] = EWV[r1][2];                       \
                z3[0] = EWV[r0][3]; z3[1] = EWV[r1][3];                       \
            }                                                                 \
            f32x2 A, B, C, D;                                                 \
            A[0] = __builtin_amdgcn_exp2f(z0[0]); A[1] = __builtin_amdgcn_exp2f(z0[1]); \
            B[0] = __builtin_amdgcn_exp2f(z1[0]); B[1] = __builtin_amdgcn_exp2f(z1[1]); \
            C[0] = __builtin_amdgcn_exp2f(z2[0]); C[1] = __builtin_amdgcn_exp2f(z2[1]); \
            D[0] = __builtin_amdgcn_exp2f(z3[0]); D[1] = __builtin_amdgcn_exp2f(z3[1]); \
            const f32x2 di = A + 1.0f, df = B + 1.0f, dg = C + 1.0f;          \
            const f32x2 m1 = di * dg;                                         \
            const f32x2 num = cP[p] * m1 + (C - 1.0f) * df;                   \
            const f32x2 qa = m1 * df;                                         \
            f32x2 Q;                                                          \
            Q[0] = __builtin_amdgcn_rcpf(qa[0]);                              \
            Q[1] = __builtin_amdgcn_rcpf(qa[1]);                              \
            cP[p] = num * Q;                                                  \
            const f32x2 cs = cP[p] * SCALE_G;                                 \
            f32x2 E2;                                                         \
            E2[0] = __builtin_amdgcn_exp2f(cs[0]);                            \
            E2[1] = __builtin_amdgcn_exp2f(cs[1]);                            \
            const f32x2 nh = E2 - 1.0f;                                       \
            const f32x2 Ph = (D + 1.0f) * (E2 + 1.0f);                        \
            f32x2 R;                                                          \
            R[0] = __builtin_amdgcn_rcpf(Ph[0]);                              \
            R[1] = __builtin_amdgcn_rcpf(Ph[1]);                              \
            const f32x2 h = nh * R;                                           \
            _Pragma("unroll")                                                 \
            for (int e = 0; e < 2; ++e) {                                     \
                const int r = 2 * p + e;                                      \
                if (WRITE_OUT) {                                              \
                    out[(seq0 + 4 * q + r) * H_N + c16] = h[e];               \
                } else {                                                      \
                    *(ushort*)((HN) + offW[r]) = bf16_rne(h[e]);              \
                }                                                             \
            }                                                                 \
        }                                                                     \
    }

#define PREFETCH_EW(EWV, T1)                                                  \
    {                                                                         \
        const i32x4 cv = *(const i32x4*)&ibuf[(T1)][4 * q];                   \
        _Pragma("unroll")                                                     \
        for (int r = 0; r < 4; ++r)                                           \
            EWV[r] = *(const f32x4*)(ewbase + (uint)(cv[r]) + c16b);          \
    }

    // single-term: 8 MFMA, 2-deep chains, zero-C first op
#define MFMA_CLUSTER(RB)                                                      \
    {                                                                         \
        const bf16x8 ah0 = *(const bf16x8*)((RB) + offA0);                    \
        const bf16x8 ah1 = *(const bf16x8*)((RB) + offA1);                    \
        __builtin_amdgcn_s_setprio(1);                                        \
        _Pragma("unroll")                                                     \
        for (int tile = 0; tile < 4; ++tile)                                  \
            acc[tile] = __builtin_amdgcn_mfma_f32_16x16x32_bf16(              \
                ah0, bh[tile][0], zero4, 0, 0, 0);                            \
        _Pragma("unroll")                                                     \
        for (int tile = 0; tile < 4; ++tile)                                  \
            acc[tile] = __builtin_amdgcn_mfma_f32_16x16x32_bf16(              \
                ah1, bh[tile][1], acc[tile], 0, 0, 0);                        \
        __builtin_amdgcn_s_setprio(0);                                        \
    }

    char* b0 = (char*)&hbuf[0][0];
    char* b1 = (char*)&hbuf[1][0];

    // ---- t = 0 (peeled): z = x-proj only (ewvA), h0 -> buf0 ----
    PREFETCH_EW(ewvA, 0);
    ACT_BODY(b0, ewvA, 0, 0);
    PREFETCH_EW(ewvB, 1);
    LBAR();

    // ---- t = 1..22 as 11 static-parity pairs ----
    // odd t consumes ewvB, even t consumes ewvA; prefetch fills the other.
    for (int tp = 0; tp < 11; ++tp) {
        // odd t: read buf0, write buf1
        MFMA_CLUSTER(b0);
        PREFETCH_EW(ewvA, 2 * tp + 2);
        ACT_BODY(b1, ewvB, 1, 0);
        LBAR();
        // even t: read buf1, write buf0
        MFMA_CLUSTER(b1);
        PREFETCH_EW(ewvB, 2 * tp + 3);
        ACT_BODY(b0, ewvA, 1, 0);
        LBAR();
    }

    // ---- t = 23: read buf0, write buf1 ----
    MFMA_CLUSTER(b0);
    PREFETCH_EW(ewvA, 24);
    ACT_BODY(b1, ewvB, 1, 0);
    LBAR();

    // ---- t = 24 (peeled): read buf1, write h_last to GLOBAL ----
    MFMA_CLUSTER(b1);
    ACT_BODY(b1, ewvA, 1, 1);

#undef ACT_BODY
#undef PREFETCH_EW
#undef MFMA_CLUSTER
}

extern "C" void kernel_launch(void* const* d_in, const int* in_sizes, int n_in,
                              void* d_out, int out_size, void* d_ws, size_t ws_size,
                              hipStream_t stream) {
    const int*   chars = (const int*)d_in[0];
    const float* E     = (const float*)d_in[1];
    const float* W     = (const float*)d_in[2];
    const float* U     = (const float*)d_in[3];
    const float* b     = (const float*)d_in[4];
    float* out = (float*)d_out;
    float*  EWr = (float*)d_ws;                         // 131072 B
    ushort* Upk = (ushort*)((char*)d_ws + 131072);      // 32768 B

    const int N = in_sizes[0] / TC_LEN;             // 32768
    const int blocks = N / SEQ_M;                   // 2048

    ew_precompute<<<V_N, G4_N, 0, stream>>>(E, W, b, EWr);
    u_pack<<<H_N, G4_N, 0, stream>>>(U, Upk);
    char_lstm_mfma<<<blocks, 256, 0, stream>>>(chars, Upk, EWr, out);
}